// Round 1
// baseline (487.548 us; speedup 1.0000x reference)
//
#include <hip/hip_runtime.h>
#include <math.h>

// Problem constants
#define B_   16
#define C_   128
#define H_   32
#define W_   32
#define D_   64
#define K_   8192
#define HW_  (H_*W_)       // 1024
#define N_   (B_*HW_)      // 16384
#define KSPLIT 16
#define KPB  (K_/KSPLIT)   // 512 codes per block
#define KCH  128           // codes per LDS chunk

// ---------------- Kernel 1: 1x1 conv + BN -> z_e [N_, 64] ----------------
// Block handles 64 positions x 64 d; thread computes 4x4.
__global__ __launch_bounds__(256) void k_proj(
    const float* __restrict__ z, const float* __restrict__ pw,
    const float* __restrict__ pb, const float* __restrict__ gamma,
    const float* __restrict__ beta, const float* __restrict__ rmean,
    const float* __restrict__ rvar, float* __restrict__ ze)
{
    __shared__ float zt[64][132];   // [pos][c], padded
    __shared__ float wl[64][132];   // [d][c],   padded
    const int tid = threadIdx.x;
    const int n0  = blockIdx.x * 64;
    const int b   = n0 / HW_;
    const int hw0 = n0 % HW_;
    const float* zb = z + (size_t)b * C_ * HW_ + hw0;

    #pragma unroll
    for (int it = 0; it < 32; ++it) {            // 64 pos * 128 c = 8192
        int flat = tid + 256 * it;
        int c = flat >> 6, p = flat & 63;
        zt[p][c] = zb[c * HW_ + p];              // coalesced global read
    }
    #pragma unroll
    for (int it = 0; it < 32; ++it) {            // 64 d * 128 c
        int flat = tid + 256 * it;
        int d = flat >> 7, c = flat & 127;
        wl[d][c] = pw[d * C_ + c];
    }
    __syncthreads();

    const int tp = tid & 15;   // position group (4 each)
    const int td = tid >> 4;   // d group (4 each)
    float acc[4][4] = {};
    #pragma unroll
    for (int c4 = 0; c4 < 32; ++c4) {
        float4 zv[4], wv[4];
        #pragma unroll
        for (int i = 0; i < 4; ++i) zv[i] = *(const float4*)&zt[4*tp + i][4*c4];
        #pragma unroll
        for (int j = 0; j < 4; ++j) wv[j] = *(const float4*)&wl[4*td + j][4*c4];
        #pragma unroll
        for (int i = 0; i < 4; ++i)
            #pragma unroll
            for (int j = 0; j < 4; ++j)
                acc[i][j] += zv[i].x*wv[j].x + zv[i].y*wv[j].y
                           + zv[i].z*wv[j].z + zv[i].w*wv[j].w;
    }

    float sc[4], bi[4];
    #pragma unroll
    for (int j = 0; j < 4; ++j) {
        int d = 4*td + j;
        float s = gamma[d] / sqrtf(rvar[d] + 1e-5f);
        sc[j] = s;
        bi[j] = pb[d] * s + beta[d] - rmean[d] * s;
    }
    #pragma unroll
    for (int i = 0; i < 4; ++i) {
        int n = n0 + 4*tp + i;
        float4 o;
        o.x = acc[i][0]*sc[0] + bi[0];
        o.y = acc[i][1]*sc[1] + bi[1];
        o.z = acc[i][2]*sc[2] + bi[2];
        o.w = acc[i][3]*sc[3] + bi[3];
        *(float4*)&ze[(size_t)n * D_ + 4*td] = o;
    }
}

// ---------------- Kernel 2: hn[k] = 0.5 * ||embed_k||^2 ----------------
__global__ __launch_bounds__(256) void k_hnorm(const float* __restrict__ e,
                                               float* __restrict__ hn)
{
    int t = blockIdx.x * 256 + threadIdx.x;      // K_*64/4 threads
    float4 v = ((const float4*)e)[t];
    float s = v.x*v.x + v.y*v.y + v.z*v.z + v.w*v.w;
    s += __shfl_xor(s, 1);
    s += __shfl_xor(s, 2);
    s += __shfl_xor(s, 4);
    s += __shfl_xor(s, 8);
    if ((threadIdx.x & 15) == 0) hn[t >> 4] = 0.5f * s;
}

// ---------------- Kernel 3: scores + per-row partial argmax ----------------
// grid (KSPLIT, N_/256); lane owns one row (z in 64 VGPRs), codes staged in LDS,
// all e/hn reads wave-uniform (broadcast, conflict-free).
__global__ __launch_bounds__(256) void k_score(
    const float* __restrict__ ze, const float* __restrict__ embed,
    const float* __restrict__ hn, float* __restrict__ pval,
    int* __restrict__ pidx)
{
    __shared__ float4 el[KCH * 16];   // 128 codes x 64 floats = 32 KB
    __shared__ float  hl[KCH];
    const int tid = threadIdx.x;
    const int ks  = blockIdx.x;       // k-split
    const int nb  = blockIdx.y;
    const int n   = nb * 256 + tid;

    float4 zr[16];
    const float4* zp = (const float4*)(ze + (size_t)n * D_);
    #pragma unroll
    for (int i = 0; i < 16; ++i) zr[i] = zp[i];

    float best = -INFINITY;
    int   bidx = 0;
    const int k0 = ks * KPB;

    for (int ch = 0; ch < KPB / KCH; ++ch) {     // 4 chunks
        __syncthreads();
        const float4* ep = (const float4*)(embed + (size_t)(k0 + ch*KCH) * D_);
        #pragma unroll
        for (int i = 0; i < 8; ++i) el[tid + 256*i] = ep[tid + 256*i];
        if (tid < KCH) hl[tid] = hn[k0 + ch*KCH + tid];
        __syncthreads();

        for (int kk = 0; kk < KCH; ++kk) {
            const float4* er = &el[kk * 16];
            float a0 = -hl[kk], a1 = 0.f;
            #pragma unroll
            for (int d4 = 0; d4 < 8; ++d4) {
                float4 e = er[d4];
                a0 += zr[d4].x*e.x + zr[d4].y*e.y + zr[d4].z*e.z + zr[d4].w*e.w;
            }
            #pragma unroll
            for (int d4 = 8; d4 < 16; ++d4) {
                float4 e = er[d4];
                a1 += zr[d4].x*e.x + zr[d4].y*e.y + zr[d4].z*e.z + zr[d4].w*e.w;
            }
            float acc = a0 + a1;
            int kg = k0 + ch*KCH + kk;
            if (acc > best) { best = acc; bidx = kg; }   // strict >: first index wins
        }
    }
    pval[ks * N_ + n] = best;
    pidx[ks * N_ + n] = bidx;
}

// ---------------- Kernel 4: finalize per row ----------------
__global__ __launch_bounds__(256) void k_final(
    const float* __restrict__ pval, const int* __restrict__ pidx,
    const float* __restrict__ embed, const float* __restrict__ ze,
    float* __restrict__ out0, float* __restrict__ outIdx,
    float* __restrict__ bsum)
{
    const int tid = threadIdx.x;
    const int n   = blockIdx.x * 256 + tid;

    float best = -INFINITY;
    int   bidx = 0;
    #pragma unroll
    for (int s = 0; s < KSPLIT; ++s) {          // ascending k: strict > keeps first
        float v = pval[s * N_ + n];
        int   id = pidx[s * N_ + n];
        if (v > best) { best = v; bidx = id; }
    }
    outIdx[n] = (float)bidx;

    const float4* eq = (const float4*)(embed + (size_t)bidx * D_);
    const float4* zq = (const float4*)(ze + (size_t)n * D_);
    const int b = n >> 10, hw = n & 1023;
    float* o = out0 + (size_t)b * (D_ * HW_) + hw;

    float local = 0.f;
    #pragma unroll
    for (int d4 = 0; d4 < 16; ++d4) {
        float4 e = eq[d4], zv = zq[d4];
        float dx = e.x - zv.x, dy = e.y - zv.y, dz = e.z - zv.z, dw = e.w - zv.w;
        local += dx*dx + dy*dy + dz*dz + dw*dw;
        o[(4*d4 + 0) * HW_] = e.x;               // coalesced across lanes (hw contiguous)
        o[(4*d4 + 1) * HW_] = e.y;
        o[(4*d4 + 2) * HW_] = e.z;
        o[(4*d4 + 3) * HW_] = e.w;
    }

    __shared__ float red[256];
    red[tid] = local;
    __syncthreads();
    for (int s = 128; s > 0; s >>= 1) {
        if (tid < s) red[tid] += red[tid + s];
        __syncthreads();
    }
    if (tid == 0) bsum[blockIdx.x] = red[0];
}

// ---------------- Kernel 5: diff scalar ----------------
__global__ void k_diff(const float* __restrict__ bsum, float* __restrict__ outd)
{
    float s = bsum[threadIdx.x];                 // 64 threads
    s += __shfl_xor(s, 1);
    s += __shfl_xor(s, 2);
    s += __shfl_xor(s, 4);
    s += __shfl_xor(s, 8);
    s += __shfl_xor(s, 16);
    s += __shfl_xor(s, 32);
    // diff = KLD_SCALE*(COMMIT*mean + mean) = 12.5 * sum / (N_*D_)
    if (threadIdx.x == 0) *outd = s * (12.5f / (float)(N_ * D_));
}

extern "C" void kernel_launch(void* const* d_in, const int* in_sizes, int n_in,
                              void* d_out, int out_size, void* d_ws, size_t ws_size,
                              hipStream_t stream)
{
    const float* z     = (const float*)d_in[0];
    const float* pw    = (const float*)d_in[1];
    const float* pb    = (const float*)d_in[2];
    const float* gamma = (const float*)d_in[3];
    const float* beta  = (const float*)d_in[4];
    const float* rmean = (const float*)d_in[5];
    const float* rvar  = (const float*)d_in[6];
    const float* embed = (const float*)d_in[7];

    float* out = (float*)d_out;
    float* out0    = out;                     // [B,D,H,W] = 1048576
    float* outDiff = out + (size_t)N_ * D_;   // 1 scalar
    float* outIdx  = outDiff + 1;             // [B,H,W] = 16384 (as float values)

    // Workspace layout (bytes)
    char* ws = (char*)d_ws;
    float* ze   = (float*)(ws);                               // 4 MB
    float* hn   = (float*)(ws + (size_t)N_ * D_ * 4);         // 32 KB
    float* pval = (float*)(ws + (size_t)N_ * D_ * 4 + K_ * 4);            // 1 MB
    int*   pidx = (int*)  (ws + (size_t)N_ * D_ * 4 + K_ * 4 + (size_t)KSPLIT * N_ * 4); // 1 MB
    float* bsum = (float*)(ws + (size_t)N_ * D_ * 4 + K_ * 4 + (size_t)KSPLIT * N_ * 8); // 256 B

    k_proj<<<N_ / 64, 256, 0, stream>>>(z, pw, pb, gamma, beta, rmean, rvar, ze);
    k_hnorm<<<(K_ * D_ / 4) / 256, 256, 0, stream>>>(embed, hn);
    k_score<<<dim3(KSPLIT, N_ / 256), 256, 0, stream>>>(ze, embed, hn, pval, pidx);
    k_final<<<N_ / 256, 256, 0, stream>>>(pval, pidx, embed, ze, out0, outIdx, bsum);
    k_diff<<<1, 64, 0, stream>>>(bsum, outDiff);
}

// Round 2
// 418.974 us; speedup vs baseline: 1.1637x; 1.1637x over previous
//
#include <hip/hip_runtime.h>
#include <math.h>

// Problem constants
#define B_   16
#define C_   128
#define H_   32
#define W_   32
#define D_   64
#define K_   8192
#define HW_  (H_*W_)       // 1024
#define N_   (B_*HW_)      // 16384
#define KSPLIT 16
#define KPB  (K_/KSPLIT)   // 512 codes per k-split block

// ---------------- Kernel 1: 1x1 conv + BN -> z_e [N_, 64] ----------------
__global__ __launch_bounds__(256) void k_proj(
    const float* __restrict__ z, const float* __restrict__ pw,
    const float* __restrict__ pb, const float* __restrict__ gamma,
    const float* __restrict__ beta, const float* __restrict__ rmean,
    const float* __restrict__ rvar, float* __restrict__ ze)
{
    __shared__ float zt[64][132];   // [pos][c], padded
    __shared__ float wl[64][132];   // [d][c],   padded
    const int tid = threadIdx.x;
    const int n0  = blockIdx.x * 64;
    const int b   = n0 / HW_;
    const int hw0 = n0 % HW_;
    const float* zb = z + (size_t)b * C_ * HW_ + hw0;

    #pragma unroll
    for (int it = 0; it < 32; ++it) {
        int flat = tid + 256 * it;
        int c = flat >> 6, p = flat & 63;
        zt[p][c] = zb[c * HW_ + p];
    }
    #pragma unroll
    for (int it = 0; it < 32; ++it) {
        int flat = tid + 256 * it;
        int d = flat >> 7, c = flat & 127;
        wl[d][c] = pw[d * C_ + c];
    }
    __syncthreads();

    const int tp = tid & 15;
    const int td = tid >> 4;
    float acc[4][4] = {};
    #pragma unroll
    for (int c4 = 0; c4 < 32; ++c4) {
        float4 zv[4], wv[4];
        #pragma unroll
        for (int i = 0; i < 4; ++i) zv[i] = *(const float4*)&zt[4*tp + i][4*c4];
        #pragma unroll
        for (int j = 0; j < 4; ++j) wv[j] = *(const float4*)&wl[4*td + j][4*c4];
        #pragma unroll
        for (int i = 0; i < 4; ++i)
            #pragma unroll
            for (int j = 0; j < 4; ++j)
                acc[i][j] += zv[i].x*wv[j].x + zv[i].y*wv[j].y
                           + zv[i].z*wv[j].z + zv[i].w*wv[j].w;
    }

    float sc[4], bi[4];
    #pragma unroll
    for (int j = 0; j < 4; ++j) {
        int d = 4*td + j;
        float s = gamma[d] / sqrtf(rvar[d] + 1e-5f);
        sc[j] = s;
        bi[j] = pb[d] * s + beta[d] - rmean[d] * s;
    }
    #pragma unroll
    for (int i = 0; i < 4; ++i) {
        int n = n0 + 4*tp + i;
        float4 o;
        o.x = acc[i][0]*sc[0] + bi[0];
        o.y = acc[i][1]*sc[1] + bi[1];
        o.z = acc[i][2]*sc[2] + bi[2];
        o.w = acc[i][3]*sc[3] + bi[3];
        *(float4*)&ze[(size_t)n * D_ + 4*td] = o;
    }
}

// ---------------- Kernel 2: hn[k] = 0.5 * ||embed_k||^2 ----------------
__global__ __launch_bounds__(256) void k_hnorm(const float* __restrict__ e,
                                               float* __restrict__ hn)
{
    int t = blockIdx.x * 256 + threadIdx.x;
    float4 v = ((const float4*)e)[t];
    float s = v.x*v.x + v.y*v.y + v.z*v.z + v.w*v.w;
    s += __shfl_xor(s, 1);
    s += __shfl_xor(s, 2);
    s += __shfl_xor(s, 4);
    s += __shfl_xor(s, 8);
    if ((threadIdx.x & 15) == 0) hn[t >> 4] = 0.5f * s;
}

// ---------------- Kernel 3: scores + per-row partial argmax ----------------
// No LDS. Each lane owns TWO rows fully in VGPRs (128 regs). The embed row is
// wave-uniform -> compiler promotes to s_load; FMAs consume it as the SGPR
// operand (v_fmac v, s, v). LDS return-bandwidth bottleneck eliminated.
__global__ __launch_bounds__(256) void k_score(
    const float* __restrict__ ze, const float* __restrict__ embed,
    const float* __restrict__ hn, float* __restrict__ pval,
    int* __restrict__ pidx)
{
    const int tid = threadIdx.x;
    const int ks  = blockIdx.x;              // k-split
    const int nb  = blockIdx.y;              // row block of 512
    const int n0  = nb * 512 + tid;
    const int n1  = n0 + 256;

    float4 z0[16], z1[16];
    const float4* zp0 = (const float4*)(ze + (size_t)n0 * D_);
    const float4* zp1 = (const float4*)(ze + (size_t)n1 * D_);
    #pragma unroll
    for (int i = 0; i < 16; ++i) z0[i] = zp0[i];
    #pragma unroll
    for (int i = 0; i < 16; ++i) z1[i] = zp1[i];

    float best0 = -INFINITY, best1 = -INFINITY;
    int   bi0 = 0, bi1 = 0;
    const int k0 = ks * KPB;

    for (int k = k0; k < k0 + KPB; ++k) {
        const float4* ep = (const float4*)(embed + (size_t)k * D_);  // uniform
        const float h = hn[k];                                        // uniform
        float s0a = 0.f, s0b = 0.f, s1a = 0.f, s1b = 0.f;
        #pragma unroll
        for (int d4 = 0; d4 < 16; d4 += 2) {
            float4 ea = ep[d4], eb = ep[d4 + 1];
            s0a += ea.x*z0[d4].x + ea.y*z0[d4].y + ea.z*z0[d4].z + ea.w*z0[d4].w;
            s1a += ea.x*z1[d4].x + ea.y*z1[d4].y + ea.z*z1[d4].z + ea.w*z1[d4].w;
            s0b += eb.x*z0[d4+1].x + eb.y*z0[d4+1].y + eb.z*z0[d4+1].z + eb.w*z0[d4+1].w;
            s1b += eb.x*z1[d4+1].x + eb.y*z1[d4+1].y + eb.z*z1[d4+1].z + eb.w*z1[d4+1].w;
        }
        float s0 = (s0a + s0b) - h;
        float s1 = (s1a + s1b) - h;
        if (s0 > best0) { best0 = s0; bi0 = k; }   // strict >: first index wins
        if (s1 > best1) { best1 = s1; bi1 = k; }
    }
    pval[ks * N_ + n0] = best0;
    pidx[ks * N_ + n0] = bi0;
    pval[ks * N_ + n1] = best1;
    pidx[ks * N_ + n1] = bi1;
}

// ---------------- Kernel 4: finalize per row ----------------
__global__ __launch_bounds__(256) void k_final(
    const float* __restrict__ pval, const int* __restrict__ pidx,
    const float* __restrict__ embed, const float* __restrict__ ze,
    float* __restrict__ out0, float* __restrict__ outIdx,
    float* __restrict__ bsum)
{
    const int tid = threadIdx.x;
    const int n   = blockIdx.x * 256 + tid;

    float best = -INFINITY;
    int   bidx = 0;
    #pragma unroll
    for (int s = 0; s < KSPLIT; ++s) {          // ascending k: strict > keeps first
        float v = pval[s * N_ + n];
        int   id = pidx[s * N_ + n];
        if (v > best) { best = v; bidx = id; }
    }
    outIdx[n] = (float)bidx;

    const float4* eq = (const float4*)(embed + (size_t)bidx * D_);
    const float4* zq = (const float4*)(ze + (size_t)n * D_);
    const int b = n >> 10, hw = n & 1023;
    float* o = out0 + (size_t)b * (D_ * HW_) + hw;

    float local = 0.f;
    #pragma unroll
    for (int d4 = 0; d4 < 16; ++d4) {
        float4 e = eq[d4], zv = zq[d4];
        float dx = e.x - zv.x, dy = e.y - zv.y, dz = e.z - zv.z, dw = e.w - zv.w;
        local += dx*dx + dy*dy + dz*dz + dw*dw;
        o[(4*d4 + 0) * HW_] = e.x;
        o[(4*d4 + 1) * HW_] = e.y;
        o[(4*d4 + 2) * HW_] = e.z;
        o[(4*d4 + 3) * HW_] = e.w;
    }

    __shared__ float red[256];
    red[tid] = local;
    __syncthreads();
    for (int s = 128; s > 0; s >>= 1) {
        if (tid < s) red[tid] += red[tid + s];
        __syncthreads();
    }
    if (tid == 0) bsum[blockIdx.x] = red[0];
}

// ---------------- Kernel 5: diff scalar ----------------
__global__ void k_diff(const float* __restrict__ bsum, float* __restrict__ outd)
{
    float s = bsum[threadIdx.x];
    s += __shfl_xor(s, 1);
    s += __shfl_xor(s, 2);
    s += __shfl_xor(s, 4);
    s += __shfl_xor(s, 8);
    s += __shfl_xor(s, 16);
    s += __shfl_xor(s, 32);
    if (threadIdx.x == 0) *outd = s * (12.5f / (float)(N_ * D_));
}

extern "C" void kernel_launch(void* const* d_in, const int* in_sizes, int n_in,
                              void* d_out, int out_size, void* d_ws, size_t ws_size,
                              hipStream_t stream)
{
    const float* z     = (const float*)d_in[0];
    const float* pw    = (const float*)d_in[1];
    const float* pb    = (const float*)d_in[2];
    const float* gamma = (const float*)d_in[3];
    const float* beta  = (const float*)d_in[4];
    const float* rmean = (const float*)d_in[5];
    const float* rvar  = (const float*)d_in[6];
    const float* embed = (const float*)d_in[7];

    float* out = (float*)d_out;
    float* out0    = out;                     // [B,D,H,W]
    float* outDiff = out + (size_t)N_ * D_;   // scalar
    float* outIdx  = outDiff + 1;             // [B,H,W]

    char* ws = (char*)d_ws;
    float* ze   = (float*)(ws);
    float* hn   = (float*)(ws + (size_t)N_ * D_ * 4);
    float* pval = (float*)(ws + (size_t)N_ * D_ * 4 + K_ * 4);
    int*   pidx = (int*)  (ws + (size_t)N_ * D_ * 4 + K_ * 4 + (size_t)KSPLIT * N_ * 4);
    float* bsum = (float*)(ws + (size_t)N_ * D_ * 4 + K_ * 4 + (size_t)KSPLIT * N_ * 8);

    k_proj<<<N_ / 64, 256, 0, stream>>>(z, pw, pb, gamma, beta, rmean, rvar, ze);
    k_hnorm<<<(K_ * D_ / 4) / 256, 256, 0, stream>>>(embed, hn);
    k_score<<<dim3(KSPLIT, N_ / 512), 256, 0, stream>>>(ze, embed, hn, pval, pidx);
    k_final<<<N_ / 256, 256, 0, stream>>>(pval, pidx, embed, ze, out0, outIdx, bsum);
    k_diff<<<1, 64, 0, stream>>>(bsum, outDiff);
}